// Round 8
// baseline (1326.643 us; speedup 1.0000x reference)
//
#include <hip/hip_runtime.h>
#include <math.h>

#define D 768
#define H 12
#define DH 64
#define S 1024
#define B 2
#define EPS 1e-6f
#define NSPLIT 2

typedef __attribute__((ext_vector_type(8))) short bf16x8;   // 8 bf16 = 4 VGPR
typedef __attribute__((ext_vector_type(4))) float f32x4;
typedef unsigned short ushort_t;

static constexpr int BSD = B * S * D;   // 1,572,864 elems per [B,S,D]
static constexpr int M2  = B * S;       // 2048
static constexpr int BHS = B * H * S;   // 24576 (row,head) rows

// ---- weight segment offsets (elements) in the packed hi/lo weight arrays ----
static constexpr size_t SZ_P    = (size_t)4 * D * D;          // (2,2,D,D)
static constexpr size_t OFF_WQ  = 0;
static constexpr size_t OFF_WK  = OFF_WQ + SZ_P;
static constexpr size_t OFF_WV  = OFF_WK + SZ_P;
static constexpr size_t OFF_WO  = OFF_WV + SZ_P;
static constexpr size_t OFF_F1  = OFF_WO + SZ_P;
static constexpr size_t OFF_F2  = OFF_F1 + SZ_P;
static constexpr size_t OFF_PW  = OFF_F2 + SZ_P;
static constexpr size_t OFF_FIN = OFF_PW + (size_t)2 * S * S;
static constexpr size_t TOTW    = OFF_FIN + (size_t)2 * D * 2 * D;  // 18,612,224

// ---------------------------------------------------------------------------
// fp32 <-> bf16 split helpers (RNE). x ~= hi + lo, |err| ~ 2^-17 |x|.
// ---------------------------------------------------------------------------
__device__ __forceinline__ ushort_t f2bf(float x) {
    unsigned u = __float_as_uint(x);
    return (ushort_t)((u + 0x7FFFu + ((u >> 16) & 1u)) >> 16);
}
__device__ __forceinline__ float bf2f(ushort_t b) {
    return __uint_as_float(((unsigned)b) << 16);
}
__device__ __forceinline__ void split_store(float v, ushort_t* ph, ushort_t* pl, size_t i) {
    ushort_t hb = f2bf(v);
    ph[i] = hb;
    pl[i] = f2bf(v - bf2f(hb));
}

// ---------------------------------------------------------------------------
// MFMA fragment-layout convention (16x16x32 bf16): see prior rounds.
// Only the C/D layout (HW-verified: row=(l>>4)*4+r, col=l&15) is load-bearing;
// intra-k permutation errors cancel (both operands packed with same map).
// LDS frag-slot order: subtile = 16(row/col) x 32(k); slot s = (row&15)+16*kc,
// fragment read = ds_read_b128 at subtile_base + lane*16.
// Swizzle (V and P regions only): phys = slot ^ ((slot>>3)&3). Key depends on
// bits 3-4 which the XOR leaves untouched -> write/read consistent involution.
// ---------------------------------------------------------------------------

// ---------------------------------------------------------------------------
// One-shot weight split: all 8 fp32 weight tensors -> packed bf16 hi/lo.
// ---------------------------------------------------------------------------
__global__ __launch_bounds__(256) void k_split_weights(
    const float* __restrict__ wq, const float* __restrict__ wk,
    const float* __restrict__ wv, const float* __restrict__ wo,
    const float* __restrict__ f1, const float* __restrict__ f2,
    const float* __restrict__ pw, const float* __restrict__ fin,
    ushort_t* __restrict__ WH, ushort_t* __restrict__ WL)
{
    size_t i = ((size_t)blockIdx.x * 256 + threadIdx.x) * 4;
    if (i >= TOTW) return;
    const float* src; size_t rel;
    if      (i < OFF_WK)  { src = wq;  rel = i; }
    else if (i < OFF_WV)  { src = wk;  rel = i - OFF_WK; }
    else if (i < OFF_WO)  { src = wv;  rel = i - OFF_WV; }
    else if (i < OFF_F1)  { src = wo;  rel = i - OFF_WO; }
    else if (i < OFF_F2)  { src = f1;  rel = i - OFF_F1; }
    else if (i < OFF_PW)  { src = f2;  rel = i - OFF_F2; }
    else if (i < OFF_FIN) { src = pw;  rel = i - OFF_PW; }
    else                  { src = fin; rel = i - OFF_FIN; }
    float4 v = *(const float4*)(src + rel);
    float xs[4] = {v.x, v.y, v.z, v.w};
    ushort4 hv, lv;
    ushort_t* hp = (ushort_t*)&hv; ushort_t* lp = (ushort_t*)&lv;
#pragma unroll
    for (int j = 0; j < 4; ++j) {
        ushort_t hb = f2bf(xs[j]);
        hp[j] = hb; lp[j] = f2bf(xs[j] - bf2f(hb));
    }
    *(ushort4*)(WH + i) = hv;
    *(ushort4*)(WL + i) = lv;
}

// ---------------------------------------------------------------------------
// [S,B,D] -> [B,S,D], emitting the bf16 hi/lo pair.
// ---------------------------------------------------------------------------
__global__ void k_sb2bs(const float* __restrict__ in,
                        ushort_t* __restrict__ oh, ushort_t* __restrict__ ol) {
    int idx = blockIdx.x * 256 + threadIdx.x;
    if (idx >= BSD) return;
    int d = idx % D; int t = idx / D; int s = t % S; int b = t / S;
    split_store(in[(s * B + b) * D + d], oh, ol, idx);
}

// ---------------------------------------------------------------------------
// bf16x3 MFMA GEMM core: C = act( A @ W^T + bias (+ R) ).
// BK=64 (two 32-k subblocks per barrier pair). K1 and K MUST be multiples
// of 64 (all call sites: 768/1024/1536). BM=BN=64, 256 thr = 4 waves (2x2),
// wave = 32x32 out. LDS region layout: [rowblk 0..3][kblk 0..1][64 slots].
// ---------------------------------------------------------------------------
template <int ACT>
__device__ __forceinline__ void gemm_core(
    const ushort_t* __restrict__ A1h, const ushort_t* __restrict__ A1l,
    const ushort_t* __restrict__ A2h, const ushort_t* __restrict__ A2l, int K1,
    const ushort_t* __restrict__ Wh,  const ushort_t* __restrict__ Wl,
    const float* __restrict__ bias,
    const ushort_t* __restrict__ RresH, const ushort_t* __restrict__ RresL,
    float* __restrict__ Cf, int trans,
    ushort_t* __restrict__ Ch, ushort_t* __restrict__ Cl,
    int M, int N, int K, int m0, int n0)
{
    __shared__ bf16x8 LAh[512], LAl[512], LBh[512], LBl[512];   // 32 KB
    const int t = threadIdx.x;
    const int lane = t & 63, wid = t >> 6;
    const int wm = wid >> 1, wn = wid & 1;

    f32x4 acc[2][2] = {};

    for (int k0 = 0; k0 < K; k0 += 64) {
#pragma unroll
        for (int rep = 0; rep < 2; ++rep) {
            const int s    = t + rep * 256;
            const int srow = s >> 3;          // 0..63: tile row
            const int sc8  = s & 7;           // 8-elem k-chunk within 64
            const int sslot = ((srow >> 4) * 2 + (sc8 >> 2)) * 64
                            + (srow & 15) + 16 * (sc8 & 3);
            const int ka = k0 + sc8 * 8;      // K1,K multiples of 64: no straddle
            const ushort_t *Aph, *Apl; int lda, kc;
            if (ka < K1) { Aph = A1h; Apl = A1l; lda = K1;     kc = ka; }
            else         { Aph = A2h; Apl = A2l; lda = K - K1; kc = ka - K1; }
            size_t aoff = (size_t)(m0 + srow) * lda + kc;
            LAh[sslot] = *(const bf16x8*)(Aph + aoff);
            LAl[sslot] = *(const bf16x8*)(Apl + aoff);
            size_t woff = (size_t)(n0 + srow) * K + k0 + sc8 * 8;
            LBh[sslot] = *(const bf16x8*)(Wh + woff);
            LBl[sslot] = *(const bf16x8*)(Wl + woff);
        }
        __syncthreads();

#pragma unroll
        for (int kb = 0; kb < 2; ++kb) {
            bf16x8 ah[2], al[2], bh[2], bl[2];
#pragma unroll
            for (int i = 0; i < 2; ++i) {
                int rg = ((wm * 2 + i) * 2 + kb) * 64 + lane;
                ah[i] = LAh[rg]; al[i] = LAl[rg];
            }
#pragma unroll
            for (int j = 0; j < 2; ++j) {
                int rg = ((wn * 2 + j) * 2 + kb) * 64 + lane;
                bh[j] = LBh[rg]; bl[j] = LBl[rg];
            }
#pragma unroll
            for (int i = 0; i < 2; ++i)
#pragma unroll
                for (int j = 0; j < 2; ++j) {
                    acc[i][j] = __builtin_amdgcn_mfma_f32_16x16x32_bf16(ah[i], bh[j], acc[i][j], 0, 0, 0);
                    acc[i][j] = __builtin_amdgcn_mfma_f32_16x16x32_bf16(ah[i], bl[j], acc[i][j], 0, 0, 0);
                    acc[i][j] = __builtin_amdgcn_mfma_f32_16x16x32_bf16(al[i], bh[j], acc[i][j], 0, 0, 0);
                }
        }
        __syncthreads();
    }

    const int cr = lane >> 4, cc = lane & 15;
#pragma unroll
    for (int i = 0; i < 2; ++i)
#pragma unroll
        for (int r = 0; r < 4; ++r) {
            int m = m0 + (wm * 2 + i) * 16 + cr * 4 + r;
#pragma unroll
            for (int j = 0; j < 2; ++j) {
                int n = n0 + (wn * 2 + j) * 16 + cc;
                size_t o = (size_t)m * N + n;
                float v = acc[i][j][r] + bias[n];
                if (RresH) v += bf2f(RresH[o]) + bf2f(RresL[o]);
                if (ACT == 1) v = 0.5f * v * (1.0f + erff(v * 0.70710678118654752440f));
                if (Ch) split_store(v, Ch, Cl, o);
                if (Cf) {
                    size_t oo = trans ? ((size_t)((m & (S - 1)) * B + (m >> 10)) * N + n) : o;
                    Cf[oo] = v;
                }
            }
        }
}

template <int ACT>
__global__ __launch_bounds__(256) void k_gemm(
    const ushort_t* A1h, const ushort_t* A1l,
    const ushort_t* A2h, const ushort_t* A2l, int K1,
    const ushort_t* Wh,  const ushort_t* Wl,
    const float* bias,
    const ushort_t* RresH, const ushort_t* RresL,
    float* Cf, int trans, ushort_t* Ch, ushort_t* Cl,
    int M, int N, int K)
{
    gemm_core<ACT>(A1h, A1l, A2h, A2l, K1, Wh, Wl, bias, RresH, RresL,
                   Cf, trans, Ch, Cl, M, N, K, blockIdx.y * 64, blockIdx.x * 64);
}

// Merged Q/K/V projection: blockIdx.z selects target (0=Q,1=K,2=V).
__global__ __launch_bounds__(256) void k_gemm_qkv(
    const ushort_t* Aqh, const ushort_t* Aql,
    const ushort_t* Akh, const ushort_t* Akl,
    const ushort_t* WH, const ushort_t* WL, size_t wOff,
    const float* bqp, const float* bkp, const float* bvp, size_t bOff,
    ushort_t* Qh, ushort_t* Ql, ushort_t* Kh, ushort_t* Kl,
    ushort_t* Vh, ushort_t* Vl)
{
    const int z = blockIdx.z;
    const ushort_t* Ah = z ? Akh : Aqh;
    const ushort_t* Al = z ? Akl : Aql;
    size_t wsel = (z == 0) ? OFF_WQ : (z == 1) ? OFF_WK : OFF_WV;
    const ushort_t* Wh = WH + wsel + wOff;
    const ushort_t* Wl = WL + wsel + wOff;
    const float* bias = ((z == 0) ? bqp : (z == 1) ? bkp : bvp) + bOff;
    ushort_t* Ch = (z == 0) ? Qh : (z == 1) ? Kh : Vh;
    ushort_t* Cl = (z == 0) ? Ql : (z == 1) ? Kl : Vl;
    gemm_core<0>(Ah, Al, nullptr, nullptr, /*K1=*/D, Wh, Wl, bias,
                 nullptr, nullptr, nullptr, 0, Ch, Cl,
                 M2, D, D, blockIdx.y * 64, blockIdx.x * 64);
}

// ---------------------------------------------------------------------------
// Flash attention PARTIAL pass, k-split: block = 64 q-rows of one (b,h) over
// S/NSPLIT kpos. Emits unnormalized O partial + (m,l) per row.
// Swizzled V/P LDS slots: phys = slot ^ ((slot>>3)&3)  (bank-conflict fix).
// ---------------------------------------------------------------------------
__global__ __launch_bounds__(256) void k_attn_part(
    const ushort_t* __restrict__ Qh_g, const ushort_t* __restrict__ Ql_g,
    const ushort_t* __restrict__ Kh_g, const ushort_t* __restrict__ Kl_g,
    const ushort_t* __restrict__ Vh_g, const ushort_t* __restrict__ Vl_g,
    float* __restrict__ PO, float* __restrict__ PML)
{
    __shared__ bf16x8 Kh[512], Kl[512], Vh[512], Vl[512];     // 32 KB
    __shared__ bf16x8 Ph[4][128], Pl[4][128];                 // 16 KB (per-wave P)
    const int t = threadIdx.x, lane = t & 63, wid = t >> 6;
    const int q0 = blockIdx.x * 64;
    const int bh = blockIdx.y, b = bh / H, h = bh % H;
    const int split = blockIdx.z;
    const int cr = lane >> 4, cc = lane & 15;
    const int lsw = lane ^ ((lane >> 3) & 3);                 // swizzled read idx

    // Q fragments: rows q0 + wid*16 + cc, d in 2 chunks of 32
    bf16x8 qh[2], ql[2];
    {
        size_t qoff = (size_t)(b * S + q0 + wid * 16 + cc) * D + h * DH + cr * 8;
#pragma unroll
        for (int c = 0; c < 2; ++c) {
            qh[c] = *(const bf16x8*)(Qh_g + qoff + c * 32);
            ql[c] = *(const bf16x8*)(Ql_g + qoff + c * 32);
        }
    }

    float mi[4], li[4];
    f32x4 o4[4] = {};
#pragma unroll
    for (int r = 0; r < 4; ++r) { mi[r] = -1e30f; li[r] = 0.f; }

    const int kt0 = split * (S / NSPLIT);
    for (int kt = kt0; kt < kt0 + S / NSPLIT; kt += 64) {
        // stage K tile (B-frag layout, unswizzled: writes already bank-uniform)
        for (int s = t; s < 512; s += 256) {
            int kp = s >> 3, dc = s & 7;
            size_t off = (size_t)(b * S + kt + kp) * D + h * DH + dc * 8;
            int idx = ((kp >> 4) * 2 + (dc >> 2)) * 64 + (kp & 15) + 16 * (dc & 3);
            Kh[idx] = *(const bf16x8*)(Kh_g + off);
            Kl[idx] = *(const bf16x8*)(Kl_g + off);
        }
        // stage V transposed into SWIZZLED B-frag slots
        {
            int kp0 = (t >> 3) * 2, dc = t & 7;
            size_t off = (size_t)(b * S + kt + kp0) * D + h * DH + dc * 8;
            bf16x8 x0 = *(const bf16x8*)(Vh_g + off);
            bf16x8 x1 = *(const bf16x8*)(Vh_g + off + D);
            bf16x8 y0 = *(const bf16x8*)(Vl_g + off);
            bf16x8 y1 = *(const bf16x8*)(Vl_g + off + D);
            unsigned* vh32 = (unsigned*)Vh;
            unsigned* vl32 = (unsigned*)Vl;
#pragma unroll
            for (int j = 0; j < 8; ++j) {
                int d = dc * 8 + j;
                int sub  = (d >> 4) * 2 + (kp0 >> 5);
                int slot = (d & 15) + 16 * ((kp0 & 31) >> 3);
                slot ^= (slot >> 3) & 3;                      // swizzle
                int si = sub * 512 + slot * 8 + (kp0 & 7);    // short index (even)
                vh32[si >> 1] = (unsigned)(ushort_t)x0[j] | ((unsigned)(ushort_t)x1[j] << 16);
                vl32[si >> 1] = (unsigned)(ushort_t)y0[j] | ((unsigned)(ushort_t)y1[j] << 16);
            }
        }
        __syncthreads();

        // QK^T: this wave's 16 q x 64 kpos
        f32x4 sc4[4] = {};
#pragma unroll
        for (int n = 0; n < 4; ++n)
#pragma unroll
            for (int fc = 0; fc < 2; ++fc) {
                bf16x8 kh = Kh[(n * 2 + fc) * 64 + lane];
                bf16x8 kl = Kl[(n * 2 + fc) * 64 + lane];
                sc4[n] = __builtin_amdgcn_mfma_f32_16x16x32_bf16(qh[fc], kh, sc4[n], 0, 0, 0);
                sc4[n] = __builtin_amdgcn_mfma_f32_16x16x32_bf16(qh[fc], kl, sc4[n], 0, 0, 0);
                sc4[n] = __builtin_amdgcn_mfma_f32_16x16x32_bf16(ql[fc], kh, sc4[n], 0, 0, 0);
            }

        // online softmax; P (hi/lo bf16) into this wave's LDS region (swizzled)
        short* php = (short*)&Ph[wid][0];
        short* plp = (short*)&Pl[wid][0];
        float e0[4];
#pragma unroll
        for (int r = 0; r < 4; ++r) {
            float mx = -1e30f;
#pragma unroll
            for (int n = 0; n < 4; ++n) { sc4[n][r] *= 0.125f; mx = fmaxf(mx, sc4[n][r]); }
            mx = fmaxf(mx, __shfl_xor(mx, 1));
            mx = fmaxf(mx, __shfl_xor(mx, 2));
            mx = fmaxf(mx, __shfl_xor(mx, 4));
            mx = fmaxf(mx, __shfl_xor(mx, 8));
            float mnew = fmaxf(mi[r], mx);
            e0[r] = __expf(mi[r] - mnew);
            mi[r] = mnew;
            float ps = 0.f;
#pragma unroll
            for (int n = 0; n < 4; ++n) {
                float pv = __expf(sc4[n][r] - mnew);
                ps += pv;
                ushort_t phh = f2bf(pv);
                ushort_t pll = f2bf(pv - bf2f(phh));
                int slot = (cr * 4 + r) + 16 * ((cc >> 3) + 2 * (n & 1));
                slot ^= (slot >> 3) & 3;                      // swizzle
                int si = (n >> 1) * 512 + slot * 8 + (lane & 7);
                php[si] = (short)phh;
                plp[si] = (short)pll;
            }
            ps += __shfl_xor(ps, 1);
            ps += __shfl_xor(ps, 2);
            ps += __shfl_xor(ps, 4);
            ps += __shfl_xor(ps, 8);
            li[r] = li[r] * e0[r] + ps;
        }
#pragma unroll
        for (int n = 0; n < 4; ++n)
#pragma unroll
            for (int r = 0; r < 4; ++r) o4[n][r] *= e0[r];

        // cross-lane P writes must land before P-frag reads (same wave)
        asm volatile("s_waitcnt lgkmcnt(0)" ::: "memory");
        __builtin_amdgcn_sched_barrier(0);

        // PV (swizzled reads for P and V)
        bf16x8 pah[2], pal[2];
#pragma unroll
        for (int fk = 0; fk < 2; ++fk) {
            pah[fk] = Ph[wid][fk * 64 + lsw];
            pal[fk] = Pl[wid][fk * 64 + lsw];
        }
#pragma unroll
        for (int n = 0; n < 4; ++n)
#pragma unroll
            for (int fk = 0; fk < 2; ++fk) {
                bf16x8 vh = Vh[(n * 2 + fk) * 64 + lsw];
                bf16x8 vl = Vl[(n * 2 + fk) * 64 + lsw];
                o4[n] = __builtin_amdgcn_mfma_f32_16x16x32_bf16(pah[fk], vh, o4[n], 0, 0, 0);
                o4[n] = __builtin_amdgcn_mfma_f32_16x16x32_bf16(pah[fk], vl, o4[n], 0, 0, 0);
                o4[n] = __builtin_amdgcn_mfma_f32_16x16x32_bf16(pal[fk], vh, o4[n], 0, 0, 0);
            }
        __syncthreads();   // before next tile's K/V staging
    }

    // partial epilogue: unnormalized O + (m, l)
    const size_t pbase = ((size_t)split * B * H + bh) * S;
#pragma unroll
    for (int r = 0; r < 4; ++r) {
        int rowl = q0 + wid * 16 + cr * 4 + r;
#pragma unroll
        for (int n = 0; n < 4; ++n)
            PO[(pbase + rowl) * DH + n * 16 + cc] = o4[n][r];
        if (cc == 0) {
            PML[(pbase + rowl) * 2]     = mi[r];
            PML[(pbase + rowl) * 2 + 1] = li[r];
        }
    }
}

// ---------------------------------------------------------------------------
// Combine NSPLIT partials -> normalized O (bf16 hi/lo pair, [B,S,D] layout).
// ---------------------------------------------------------------------------
__global__ __launch_bounds__(256) void k_attn_combine(
    const float* __restrict__ PO, const float* __restrict__ PML,
    ushort_t* __restrict__ Oh, ushort_t* __restrict__ Ol)
{
    int i = blockIdx.x * 256 + threadIdx.x;     // over BHS*DH = 1,572,864
    if (i >= BHS * DH) return;
    int d = i & 63;
    int row = (i >> 6) & (S - 1);
    int bh = i >> 16;                            // S*DH = 65536 = 2^16
    int b = bh / H, h = bh % H;
    int mlb = (bh * S + row) * 2;
    float m0 = PML[mlb],               l0 = PML[mlb + 1];
    float m1 = PML[mlb + BHS * 2],     l1 = PML[mlb + 1 + BHS * 2];
    float M = fmaxf(m0, m1);
    float w0 = __expf(m0 - M), w1 = __expf(m1 - M);
    float L = l0 * w0 + l1 * w1;
    float o = (PO[i] * w0 + PO[i + (size_t)BHS * DH] * w1) / L;
    split_store(o, Oh, Ol, (size_t)(b * S + row) * D + h * DH + d);
}

// ---------------------------------------------------------------------------
// LayerNorm (torch custom LN: Bessel std N-1, eps added to STD).
// ---------------------------------------------------------------------------
__global__ __launch_bounds__(256) void k_ln(
    const ushort_t* __restrict__ XH, const ushort_t* __restrict__ XL,
    const float* __restrict__ g, const float* __restrict__ bb,
    ushort_t* __restrict__ YH, ushort_t* __restrict__ YL)
{
    __shared__ float red[4];
    const int row = blockIdx.x;
    const int t = threadIdx.x;
    size_t base = (size_t)row * D + t;
    float v0 = bf2f(XH[base])       + bf2f(XL[base]);
    float v1 = bf2f(XH[base + 256]) + bf2f(XL[base + 256]);
    float v2 = bf2f(XH[base + 512]) + bf2f(XL[base + 512]);
    float s = v0 + v1 + v2;
    for (int off = 32; off; off >>= 1) s += __shfl_xor(s, off);
    if ((t & 63) == 0) red[t >> 6] = s;
    __syncthreads();
    float mean = (red[0] + red[1] + red[2] + red[3]) * (1.0f / 768.0f);
    __syncthreads();
    float c0 = v0 - mean, c1 = v1 - mean, c2 = v2 - mean;
    float q = c0 * c0 + c1 * c1 + c2 * c2;
    for (int off = 32; off; off >>= 1) q += __shfl_xor(q, off);
    if ((t & 63) == 0) red[t >> 6] = q;
    __syncthreads();
    float stdv = sqrtf((red[0] + red[1] + red[2] + red[3]) * (1.0f / 767.0f));
    float inv = 1.0f / (stdv + EPS);
#pragma unroll
    for (int j = 0; j < 3; ++j) {
        float cj = (j == 0) ? c0 : (j == 1) ? c1 : c2;
        float y = g[t + j * 256] * cj * inv + bb[t + j * 256];
        split_store(y, YH, YL, base + j * 256);
    }
}

// ---------------------------------------------------------------------------
extern "C" void kernel_launch(void* const* d_in, const int* in_sizes, int n_in,
                              void* d_out, int out_size, void* d_ws, size_t ws_size,
                              hipStream_t stream) {
    const float* e    = (const float*)d_in[0];
    const float* f    = (const float*)d_in[1];
    const float* wq   = (const float*)d_in[2];
    const float* wk   = (const float*)d_in[3];
    const float* wv   = (const float*)d_in[4];
    const float* wo   = (const float*)d_in[5];
    const float* bq   = (const float*)d_in[6];
    const float* bk   = (const float*)d_in[7];
    const float* bv   = (const float*)d_in[8];
    const float* bo   = (const float*)d_in[9];
    const float* alg  = (const float*)d_in[10];
    const float* alb  = (const float*)d_in[11];
    const float* fw1  = (const float*)d_in[12];
    const float* fb1  = (const float*)d_in[13];
    const float* fw2  = (const float*)d_in[14];
    const float* fb2  = (const float*)d_in[15];
    const float* flg  = (const float*)d_in[16];
    const float* flb  = (const float*)d_in[17];
    const float* pw   = (const float*)d_in[18];
    const float* pb   = (const float*)d_in[19];
    const float* finw = (const float*)d_in[20];
    const float* finb = (const float*)d_in[21];

    // ---- workspace: 6 hi/lo pairs + split weights + attn partials (~125 MB)
    char* w = (char*)d_ws;
    ushort_t *PH[6], *PL[6];
    for (int i = 0; i < 6; ++i) {
        PH[i] = (ushort_t*)(w + (size_t)(2 * i)     * BSD * 2);
        PL[i] = (ushort_t*)(w + (size_t)(2 * i + 1) * BSD * 2);
    }
    ushort_t* WH = (ushort_t*)(w + (size_t)12 * BSD * 2);
    ushort_t* WL = WH + TOTW;
    float* PO  = (float*)(WL + TOTW);                    // NSPLIT*BHS*DH fp32
    float* PML = PO + (size_t)NSPLIT * BHS * DH;         // NSPLIT*BHS*2 fp32

    k_split_weights<<<(int)(TOTW / 4 / 256), 256, 0, stream>>>(
        wq, wk, wv, wo, fw1, fw2, pw, finw, WH, WL);

    auto gemm = [&](const ushort_t* A1h, const ushort_t* A1l,
                    const ushort_t* A2h, const ushort_t* A2l, int K1,
                    size_t wElemOff, const float* bias,
                    const ushort_t* RresH, const ushort_t* RresL,
                    float* Cf, int trans, ushort_t* Ch, ushort_t* Cl,
                    int M, int N, int K, int act) {
        dim3 g(N / 64, M / 64), blk(256);
        if (act) k_gemm<1><<<g, blk, 0, stream>>>(A1h, A1l, A2h, A2l, K1,
                     WH + wElemOff, WL + wElemOff, bias, RresH, RresL,
                     Cf, trans, Ch, Cl, M, N, K);
        else     k_gemm<0><<<g, blk, 0, stream>>>(A1h, A1l, A2h, A2l, K1,
                     WH + wElemOff, WL + wElemOff, bias, RresH, RresL,
                     Cf, trans, Ch, Cl, M, N, K);
    };

    // One transformer block; all activations as hi/lo pairs.
    auto blk_fn = [&](int qi, int kvi, int ti, int li, int outi) {
        const size_t wOff = (size_t)(ti * 2 + li) * D * D;
        const size_t bOff = (size_t)(ti * 2 + li) * D;
        k_gemm_qkv<<<dim3(D / 64, M2 / 64, 3), 256, 0, stream>>>(
            PH[qi], PL[qi], PH[kvi], PL[kvi], WH, WL, wOff, bq, bk, bv, bOff,
            PH[1], PL[1], PH[2], PL[2], PH[3], PL[3]);
        k_attn_part<<<dim3(S / 64, B * H, NSPLIT), 256, 0, stream>>>(
            PH[1], PL[1], PH[2], PL[2], PH[3], PL[3], PO, PML);
        k_attn_combine<<<(BHS * DH) / 256, 256, 0, stream>>>(PO, PML, PH[4], PL[4]);
        // O-projection + residual(q_in) -> pair 1
        gemm(PH[4], PL[4], nullptr, nullptr, D, OFF_WO + wOff, bo + bOff,
             PH[qi], PL[qi], nullptr, 0, PH[1], PL[1], M2, D, D, 0);
        k_ln<<<M2, 256, 0, stream>>>(PH[1], PL[1], alg + bOff, alb + bOff, PH[2], PL[2]);
        // FFN
        gemm(PH[2], PL[2], nullptr, nullptr, D, OFF_F1 + wOff, fb1 + bOff,
             nullptr, nullptr, nullptr, 0, PH[3], PL[3], M2, D, D, 1);
        gemm(PH[3], PL[3], nullptr, nullptr, D, OFF_F2 + wOff, fb2 + bOff,
             PH[2], PL[2], nullptr, 0, PH[4], PL[4], M2, D, D, 0);
        k_ln<<<M2, 256, 0, stream>>>(PH[4], PL[4], flg + bOff, flb + bOff, PH[outi], PL[outi]);
    };

    auto pass = [&](const float* src, const float* src1, int ti, float* out_sbd) {
        const int TGRID = BSD / 256;
        k_sb2bs<<<TGRID, 256, 0, stream>>>(src, PH[0], PL[0]);
        blk_fn(0, 0, ti, 0, 5);                                  // feats -> pair 5
        k_sb2bs<<<TGRID, 256, 0, stream>>>(src1, PH[0], PL[0]);
        blk_fn(0, 5, ti, 1, 0);                                  // cross -> pair 0
        // pool: flat [1536,1024] @ pw[ti]^T + pb -> pair 1 (APP)
        gemm(PH[0], PL[0], nullptr, nullptr, S, OFF_PW + (size_t)ti * S * S,
             pb + (size_t)ti * S, nullptr, nullptr, nullptr, 0, PH[1], PL[1],
             BSD / S, S, S, 0);
        // final: concat([feats, app]) @ finw^T + finb -> d_out ([S,B,D] direct)
        gemm(PH[5], PL[5], PH[1], PL[1], D, OFF_FIN + (size_t)ti * D * 2 * D,
             finb + (size_t)ti * D, nullptr, nullptr, out_sbd, 1, nullptr, nullptr,
             M2, D, 2 * D, 0);
    };

    float* out = (float*)d_out;
    pass(e, f, 0, out);
    pass(f, e, 1, out + (size_t)BSD);
}

// Round 9
// 941.670 us; speedup vs baseline: 1.4088x; 1.4088x over previous
//
#include <hip/hip_runtime.h>
#include <math.h>

#define D 768
#define H 12
#define DH 64
#define S 1024
#define B 2
#define EPS 1e-6f
#define NSPLIT 2

typedef __attribute__((ext_vector_type(8))) short bf16x8;   // 8 bf16 = 4 VGPR
typedef __attribute__((ext_vector_type(4))) float f32x4;
typedef unsigned short ushort_t;

static constexpr int BSD = B * S * D;   // 1,572,864 elems per [B,S,D]
static constexpr int M2  = B * S;       // 2048
static constexpr int BHS = B * H * S;   // 24576 (row,head) rows

// ---- weight segment offsets (elements) in the packed hi/lo weight arrays ----
static constexpr size_t SZ_P    = (size_t)4 * D * D;          // (2,2,D,D)
static constexpr size_t OFF_WQ  = 0;
static constexpr size_t OFF_WK  = OFF_WQ + SZ_P;
static constexpr size_t OFF_WV  = OFF_WK + SZ_P;
static constexpr size_t OFF_WO  = OFF_WV + SZ_P;
static constexpr size_t OFF_F1  = OFF_WO + SZ_P;
static constexpr size_t OFF_F2  = OFF_F1 + SZ_P;
static constexpr size_t OFF_PW  = OFF_F2 + SZ_P;
static constexpr size_t OFF_FIN = OFF_PW + (size_t)2 * S * S;
static constexpr size_t TOTW    = OFF_FIN + (size_t)2 * D * 2 * D;  // 18,612,224

// ---------------------------------------------------------------------------
// fp32 <-> bf16 split helpers (RNE). x ~= hi + lo, |err| ~ 2^-17 |x|.
// ---------------------------------------------------------------------------
__device__ __forceinline__ ushort_t f2bf(float x) {
    unsigned u = __float_as_uint(x);
    return (ushort_t)((u + 0x7FFFu + ((u >> 16) & 1u)) >> 16);
}
__device__ __forceinline__ float bf2f(ushort_t b) {
    return __uint_as_float(((unsigned)b) << 16);
}
__device__ __forceinline__ void split_store(float v, ushort_t* ph, ushort_t* pl, size_t i) {
    ushort_t hb = f2bf(v);
    ph[i] = hb;
    pl[i] = f2bf(v - bf2f(hb));
}
// Frag-array swizzle: bijective, involutive; kills the slot%8-uniform write
// conflict (8 lanes -> 1 bank group) while keeping reads >= 2-way (free).
__device__ __forceinline__ int swz(int s) { return s ^ ((s >> 4) & 7); }

// ---------------------------------------------------------------------------
// MFMA fragment-layout convention (16x16x32 bf16): see prior rounds.
// Only the C/D layout (HW-verified: row=(l>>4)*4+r, col=l&15) is load-bearing;
// intra-k permutation errors cancel (both operands packed with same map).
// LDS frag-slot order: subtile = 16(row/col) x 32(k); slot s = (row&15)+16*kc,
// fragment read = ds_read_b128 at subtile_base + lane*16. All 512-slot frag
// regions (GEMM A/B, attn K) are stored at swz(slot) (bank-conflict fix,
// measured r8: 2.48e7 conflict-cycles on unswizzled staging writes).
// V/P keep the r7 intra-subtile swizzle (working).
// ---------------------------------------------------------------------------

// ---------------------------------------------------------------------------
// One-shot weight split: all 8 fp32 weight tensors -> packed bf16 hi/lo.
// ---------------------------------------------------------------------------
__global__ __launch_bounds__(256) void k_split_weights(
    const float* __restrict__ wq, const float* __restrict__ wk,
    const float* __restrict__ wv, const float* __restrict__ wo,
    const float* __restrict__ f1, const float* __restrict__ f2,
    const float* __restrict__ pw, const float* __restrict__ fin,
    ushort_t* __restrict__ WH, ushort_t* __restrict__ WL)
{
    size_t i = ((size_t)blockIdx.x * 256 + threadIdx.x) * 4;
    if (i >= TOTW) return;
    const float* src; size_t rel;
    if      (i < OFF_WK)  { src = wq;  rel = i; }
    else if (i < OFF_WV)  { src = wk;  rel = i - OFF_WK; }
    else if (i < OFF_WO)  { src = wv;  rel = i - OFF_WV; }
    else if (i < OFF_F1)  { src = wo;  rel = i - OFF_WO; }
    else if (i < OFF_F2)  { src = f1;  rel = i - OFF_F1; }
    else if (i < OFF_PW)  { src = f2;  rel = i - OFF_F2; }
    else if (i < OFF_FIN) { src = pw;  rel = i - OFF_PW; }
    else                  { src = fin; rel = i - OFF_FIN; }
    float4 v = *(const float4*)(src + rel);
    float xs[4] = {v.x, v.y, v.z, v.w};
    ushort4 hv, lv;
    ushort_t* hp = (ushort_t*)&hv; ushort_t* lp = (ushort_t*)&lv;
#pragma unroll
    for (int j = 0; j < 4; ++j) {
        ushort_t hb = f2bf(xs[j]);
        hp[j] = hb; lp[j] = f2bf(xs[j] - bf2f(hb));
    }
    *(ushort4*)(WH + i) = hv;
    *(ushort4*)(WL + i) = lv;
}

// ---------------------------------------------------------------------------
// [S,B,D] -> [B,S,D], emitting the bf16 hi/lo pair.
// ---------------------------------------------------------------------------
__global__ void k_sb2bs(const float* __restrict__ in,
                        ushort_t* __restrict__ oh, ushort_t* __restrict__ ol) {
    int idx = blockIdx.x * 256 + threadIdx.x;
    if (idx >= BSD) return;
    int d = idx % D; int t = idx / D; int s = t % S; int b = t / S;
    split_store(in[(s * B + b) * D + d], oh, ol, idx);
}

// ---------------------------------------------------------------------------
// bf16x3 MFMA GEMM core: C = act( A @ W^T + bias (+ R) ).
// BK=64, swizzled staging. K1 and K MUST be multiples of 64. BM=BN=64,
// 256 thr = 4 waves (2x2), wave = 32x32 out.
// ---------------------------------------------------------------------------
template <int ACT>
__device__ __forceinline__ void gemm_core(
    const ushort_t* __restrict__ A1h, const ushort_t* __restrict__ A1l,
    const ushort_t* __restrict__ A2h, const ushort_t* __restrict__ A2l, int K1,
    const ushort_t* __restrict__ Wh,  const ushort_t* __restrict__ Wl,
    const float* __restrict__ bias,
    const ushort_t* __restrict__ RresH, const ushort_t* __restrict__ RresL,
    float* __restrict__ Cf, int trans,
    ushort_t* __restrict__ Ch, ushort_t* __restrict__ Cl,
    int M, int N, int K, int m0, int n0)
{
    __shared__ bf16x8 LAh[512], LAl[512], LBh[512], LBl[512];   // 32 KB
    const int t = threadIdx.x;
    const int lane = t & 63, wid = t >> 6;
    const int wm = wid >> 1, wn = wid & 1;

    f32x4 acc[2][2] = {};

    for (int k0 = 0; k0 < K; k0 += 64) {
#pragma unroll
        for (int rep = 0; rep < 2; ++rep) {
            const int s    = t + rep * 256;
            const int srow = s >> 3;          // 0..63: tile row
            const int sc8  = s & 7;           // 8-elem k-chunk within 64
            const int sslot = swz(((srow >> 4) * 2 + (sc8 >> 2)) * 64
                                  + (srow & 15) + 16 * (sc8 & 3));
            const int ka = k0 + sc8 * 8;      // K1,K multiples of 64: no straddle
            const ushort_t *Aph, *Apl; int lda, kc;
            if (ka < K1) { Aph = A1h; Apl = A1l; lda = K1;     kc = ka; }
            else         { Aph = A2h; Apl = A2l; lda = K - K1; kc = ka - K1; }
            size_t aoff = (size_t)(m0 + srow) * lda + kc;
            LAh[sslot] = *(const bf16x8*)(Aph + aoff);
            LAl[sslot] = *(const bf16x8*)(Apl + aoff);
            size_t woff = (size_t)(n0 + srow) * K + k0 + sc8 * 8;
            LBh[sslot] = *(const bf16x8*)(Wh + woff);
            LBl[sslot] = *(const bf16x8*)(Wl + woff);
        }
        __syncthreads();

#pragma unroll
        for (int kb = 0; kb < 2; ++kb) {
            bf16x8 ah[2], al[2], bh[2], bl[2];
#pragma unroll
            for (int i = 0; i < 2; ++i) {
                int rg = swz(((wm * 2 + i) * 2 + kb) * 64 + lane);
                ah[i] = LAh[rg]; al[i] = LAl[rg];
            }
#pragma unroll
            for (int j = 0; j < 2; ++j) {
                int rg = swz(((wn * 2 + j) * 2 + kb) * 64 + lane);
                bh[j] = LBh[rg]; bl[j] = LBl[rg];
            }
#pragma unroll
            for (int i = 0; i < 2; ++i)
#pragma unroll
                for (int j = 0; j < 2; ++j) {
                    acc[i][j] = __builtin_amdgcn_mfma_f32_16x16x32_bf16(ah[i], bh[j], acc[i][j], 0, 0, 0);
                    acc[i][j] = __builtin_amdgcn_mfma_f32_16x16x32_bf16(ah[i], bl[j], acc[i][j], 0, 0, 0);
                    acc[i][j] = __builtin_amdgcn_mfma_f32_16x16x32_bf16(al[i], bh[j], acc[i][j], 0, 0, 0);
                }
        }
        __syncthreads();
    }

    const int cr = lane >> 4, cc = lane & 15;
#pragma unroll
    for (int i = 0; i < 2; ++i)
#pragma unroll
        for (int r = 0; r < 4; ++r) {
            int m = m0 + (wm * 2 + i) * 16 + cr * 4 + r;
#pragma unroll
            for (int j = 0; j < 2; ++j) {
                int n = n0 + (wn * 2 + j) * 16 + cc;
                size_t o = (size_t)m * N + n;
                float v = acc[i][j][r] + bias[n];
                if (RresH) v += bf2f(RresH[o]) + bf2f(RresL[o]);
                if (ACT == 1) v = 0.5f * v * (1.0f + erff(v * 0.70710678118654752440f));
                if (Ch) split_store(v, Ch, Cl, o);
                if (Cf) {
                    size_t oo = trans ? ((size_t)((m & (S - 1)) * B + (m >> 10)) * N + n) : o;
                    Cf[oo] = v;
                }
            }
        }
}

template <int ACT>
__global__ __launch_bounds__(256) void k_gemm(
    const ushort_t* A1h, const ushort_t* A1l,
    const ushort_t* A2h, const ushort_t* A2l, int K1,
    const ushort_t* Wh,  const ushort_t* Wl,
    const float* bias,
    const ushort_t* RresH, const ushort_t* RresL,
    float* Cf, int trans, ushort_t* Ch, ushort_t* Cl,
    int M, int N, int K)
{
    gemm_core<ACT>(A1h, A1l, A2h, A2l, K1, Wh, Wl, bias, RresH, RresL,
                   Cf, trans, Ch, Cl, M, N, K, blockIdx.y * 64, blockIdx.x * 64);
}

// Merged Q/K/V projection: blockIdx.z selects target (0=Q,1=K,2=V).
__global__ __launch_bounds__(256) void k_gemm_qkv(
    const ushort_t* Aqh, const ushort_t* Aql,
    const ushort_t* Akh, const ushort_t* Akl,
    const ushort_t* WH, const ushort_t* WL, size_t wOff,
    const float* bqp, const float* bkp, const float* bvp, size_t bOff,
    ushort_t* Qh, ushort_t* Ql, ushort_t* Kh, ushort_t* Kl,
    ushort_t* Vh, ushort_t* Vl)
{
    const int z = blockIdx.z;
    const ushort_t* Ah = z ? Akh : Aqh;
    const ushort_t* Al = z ? Akl : Aql;
    size_t wsel = (z == 0) ? OFF_WQ : (z == 1) ? OFF_WK : OFF_WV;
    const ushort_t* Wh = WH + wsel + wOff;
    const ushort_t* Wl = WL + wsel + wOff;
    const float* bias = ((z == 0) ? bqp : (z == 1) ? bkp : bvp) + bOff;
    ushort_t* Ch = (z == 0) ? Qh : (z == 1) ? Kh : Vh;
    ushort_t* Cl = (z == 0) ? Ql : (z == 1) ? Kl : Vl;
    gemm_core<0>(Ah, Al, nullptr, nullptr, /*K1=*/D, Wh, Wl, bias,
                 nullptr, nullptr, nullptr, 0, Ch, Cl,
                 M2, D, D, blockIdx.y * 64, blockIdx.x * 64);
}

// ---------------------------------------------------------------------------
// Flash attention PARTIAL pass, k-split: block = 64 q-rows of one (b,h) over
// S/NSPLIT kpos. Emits unnormalized O partial + (m,l) per row.
// K region swizzled with swz(); V/P keep the r7 intra-subtile swizzle.
// ---------------------------------------------------------------------------
__global__ __launch_bounds__(256) void k_attn_part(
    const ushort_t* __restrict__ Qh_g, const ushort_t* __restrict__ Ql_g,
    const ushort_t* __restrict__ Kh_g, const ushort_t* __restrict__ Kl_g,
    const ushort_t* __restrict__ Vh_g, const ushort_t* __restrict__ Vl_g,
    float* __restrict__ PO, float* __restrict__ PML)
{
    __shared__ bf16x8 Kh[512], Kl[512], Vh[512], Vl[512];     // 32 KB
    __shared__ bf16x8 Ph[4][128], Pl[4][128];                 // 16 KB (per-wave P)
    const int t = threadIdx.x, lane = t & 63, wid = t >> 6;
    const int q0 = blockIdx.x * 64;
    const int bh = blockIdx.y, b = bh / H, h = bh % H;
    const int split = blockIdx.z;
    const int cr = lane >> 4, cc = lane & 15;
    const int lsw = lane ^ ((lane >> 3) & 3);                 // V/P swizzled idx

    // Q fragments: rows q0 + wid*16 + cc, d in 2 chunks of 32
    bf16x8 qh[2], ql[2];
    {
        size_t qoff = (size_t)(b * S + q0 + wid * 16 + cc) * D + h * DH + cr * 8;
#pragma unroll
        for (int c = 0; c < 2; ++c) {
            qh[c] = *(const bf16x8*)(Qh_g + qoff + c * 32);
            ql[c] = *(const bf16x8*)(Ql_g + qoff + c * 32);
        }
    }

    float mi[4], li[4];
    f32x4 o4[4] = {};
#pragma unroll
    for (int r = 0; r < 4; ++r) { mi[r] = -1e30f; li[r] = 0.f; }

    const int kt0 = split * (S / NSPLIT);
    for (int kt = kt0; kt < kt0 + S / NSPLIT; kt += 64) {
        // stage K tile (B-frag layout, swizzled)
        for (int s = t; s < 512; s += 256) {
            int kp = s >> 3, dc = s & 7;
            size_t off = (size_t)(b * S + kt + kp) * D + h * DH + dc * 8;
            int idx = swz(((kp >> 4) * 2 + (dc >> 2)) * 64 + (kp & 15) + 16 * (dc & 3));
            Kh[idx] = *(const bf16x8*)(Kh_g + off);
            Kl[idx] = *(const bf16x8*)(Kl_g + off);
        }
        // stage V transposed into r7-swizzled B-frag slots
        {
            int kp0 = (t >> 3) * 2, dc = t & 7;
            size_t off = (size_t)(b * S + kt + kp0) * D + h * DH + dc * 8;
            bf16x8 x0 = *(const bf16x8*)(Vh_g + off);
            bf16x8 x1 = *(const bf16x8*)(Vh_g + off + D);
            bf16x8 y0 = *(const bf16x8*)(Vl_g + off);
            bf16x8 y1 = *(const bf16x8*)(Vl_g + off + D);
            unsigned* vh32 = (unsigned*)Vh;
            unsigned* vl32 = (unsigned*)Vl;
#pragma unroll
            for (int j = 0; j < 8; ++j) {
                int d = dc * 8 + j;
                int sub  = (d >> 4) * 2 + (kp0 >> 5);
                int slot = (d & 15) + 16 * ((kp0 & 31) >> 3);
                slot ^= (slot >> 3) & 3;                      // r7 swizzle
                int si = sub * 512 + slot * 8 + (kp0 & 7);    // short index (even)
                vh32[si >> 1] = (unsigned)(ushort_t)x0[j] | ((unsigned)(ushort_t)x1[j] << 16);
                vl32[si >> 1] = (unsigned)(ushort_t)y0[j] | ((unsigned)(ushort_t)y1[j] << 16);
            }
        }
        __syncthreads();

        // QK^T: this wave's 16 q x 64 kpos
        f32x4 sc4[4] = {};
#pragma unroll
        for (int n = 0; n < 4; ++n)
#pragma unroll
            for (int fc = 0; fc < 2; ++fc) {
                int kg = swz((n * 2 + fc) * 64 + lane);
                bf16x8 kh = Kh[kg], kl = Kl[kg];
                sc4[n] = __builtin_amdgcn_mfma_f32_16x16x32_bf16(qh[fc], kh, sc4[n], 0, 0, 0);
                sc4[n] = __builtin_amdgcn_mfma_f32_16x16x32_bf16(qh[fc], kl, sc4[n], 0, 0, 0);
                sc4[n] = __builtin_amdgcn_mfma_f32_16x16x32_bf16(ql[fc], kh, sc4[n], 0, 0, 0);
            }

        // online softmax; P (hi/lo bf16) into this wave's LDS region (r7 swz)
        short* php = (short*)&Ph[wid][0];
        short* plp = (short*)&Pl[wid][0];
        float e0[4];
#pragma unroll
        for (int r = 0; r < 4; ++r) {
            float mx = -1e30f;
#pragma unroll
            for (int n = 0; n < 4; ++n) { sc4[n][r] *= 0.125f; mx = fmaxf(mx, sc4[n][r]); }
            mx = fmaxf(mx, __shfl_xor(mx, 1));
            mx = fmaxf(mx, __shfl_xor(mx, 2));
            mx = fmaxf(mx, __shfl_xor(mx, 4));
            mx = fmaxf(mx, __shfl_xor(mx, 8));
            float mnew = fmaxf(mi[r], mx);
            e0[r] = __expf(mi[r] - mnew);
            mi[r] = mnew;
            float ps = 0.f;
#pragma unroll
            for (int n = 0; n < 4; ++n) {
                float pv = __expf(sc4[n][r] - mnew);
                ps += pv;
                ushort_t phh = f2bf(pv);
                ushort_t pll = f2bf(pv - bf2f(phh));
                int slot = (cr * 4 + r) + 16 * ((cc >> 3) + 2 * (n & 1));
                slot ^= (slot >> 3) & 3;                      // r7 swizzle
                int si = (n >> 1) * 512 + slot * 8 + (lane & 7);
                php[si] = (short)phh;
                plp[si] = (short)pll;
            }
            ps += __shfl_xor(ps, 1);
            ps += __shfl_xor(ps, 2);
            ps += __shfl_xor(ps, 4);
            ps += __shfl_xor(ps, 8);
            li[r] = li[r] * e0[r] + ps;
        }
#pragma unroll
        for (int n = 0; n < 4; ++n)
#pragma unroll
            for (int r = 0; r < 4; ++r) o4[n][r] *= e0[r];

        // cross-lane P writes must land before P-frag reads (same wave)
        asm volatile("s_waitcnt lgkmcnt(0)" ::: "memory");
        __builtin_amdgcn_sched_barrier(0);

        // PV (r7-swizzled reads for P and V)
        bf16x8 pah[2], pal[2];
#pragma unroll
        for (int fk = 0; fk < 2; ++fk) {
            pah[fk] = Ph[wid][fk * 64 + lsw];
            pal[fk] = Pl[wid][fk * 64 + lsw];
        }
#pragma unroll
        for (int n = 0; n < 4; ++n)
#pragma unroll
            for (int fk = 0; fk < 2; ++fk) {
                bf16x8 vh = Vh[(n * 2 + fk) * 64 + lsw];
                bf16x8 vl = Vl[(n * 2 + fk) * 64 + lsw];
                o4[n] = __builtin_amdgcn_mfma_f32_16x16x32_bf16(pah[fk], vh, o4[n], 0, 0, 0);
                o4[n] = __builtin_amdgcn_mfma_f32_16x16x32_bf16(pah[fk], vl, o4[n], 0, 0, 0);
                o4[n] = __builtin_amdgcn_mfma_f32_16x16x32_bf16(pal[fk], vh, o4[n], 0, 0, 0);
            }
        __syncthreads();   // before next tile's K/V staging
    }

    // partial epilogue: unnormalized O + (m, l)
    const size_t pbase = ((size_t)split * B * H + bh) * S;
#pragma unroll
    for (int r = 0; r < 4; ++r) {
        int rowl = q0 + wid * 16 + cr * 4 + r;
#pragma unroll
        for (int n = 0; n < 4; ++n)
            PO[(pbase + rowl) * DH + n * 16 + cc] = o4[n][r];
        if (cc == 0) {
            PML[(pbase + rowl) * 2]     = mi[r];
            PML[(pbase + rowl) * 2 + 1] = li[r];
        }
    }
}

// ---------------------------------------------------------------------------
// Combine NSPLIT partials -> normalized O (bf16 hi/lo pair, [B,S,D] layout).
// ---------------------------------------------------------------------------
__global__ __launch_bounds__(256) void k_attn_combine(
    const float* __restrict__ PO, const float* __restrict__ PML,
    ushort_t* __restrict__ Oh, ushort_t* __restrict__ Ol)
{
    int i = blockIdx.x * 256 + threadIdx.x;     // over BHS*DH = 1,572,864
    if (i >= BHS * DH) return;
    int d = i & 63;
    int row = (i >> 6) & (S - 1);
    int bh = i >> 16;                            // S*DH = 65536 = 2^16
    int b = bh / H, h = bh % H;
    int mlb = (bh * S + row) * 2;
    float m0 = PML[mlb],               l0 = PML[mlb + 1];
    float m1 = PML[mlb + BHS * 2],     l1 = PML[mlb + 1 + BHS * 2];
    float M = fmaxf(m0, m1);
    float w0 = __expf(m0 - M), w1 = __expf(m1 - M);
    float L = l0 * w0 + l1 * w1;
    float o = (PO[i] * w0 + PO[i + (size_t)BHS * DH] * w1) / L;
    split_store(o, Oh, Ol, (size_t)(b * S + row) * D + h * DH + d);
}

// ---------------------------------------------------------------------------
// LayerNorm (torch custom LN: Bessel std N-1, eps added to STD).
// ---------------------------------------------------------------------------
__global__ __launch_bounds__(256) void k_ln(
    const ushort_t* __restrict__ XH, const ushort_t* __restrict__ XL,
    const float* __restrict__ g, const float* __restrict__ bb,
    ushort_t* __restrict__ YH, ushort_t* __restrict__ YL)
{
    __shared__ float red[4];
    const int row = blockIdx.x;
    const int t = threadIdx.x;
    size_t base = (size_t)row * D + t;
    float v0 = bf2f(XH[base])       + bf2f(XL[base]);
    float v1 = bf2f(XH[base + 256]) + bf2f(XL[base + 256]);
    float v2 = bf2f(XH[base + 512]) + bf2f(XL[base + 512]);
    float s = v0 + v1 + v2;
    for (int off = 32; off; off >>= 1) s += __shfl_xor(s, off);
    if ((t & 63) == 0) red[t >> 6] = s;
    __syncthreads();
    float mean = (red[0] + red[1] + red[2] + red[3]) * (1.0f / 768.0f);
    __syncthreads();
    float c0 = v0 - mean, c1 = v1 - mean, c2 = v2 - mean;
    float q = c0 * c0 + c1 * c1 + c2 * c2;
    for (int off = 32; off; off >>= 1) q += __shfl_xor(q, off);
    if ((t & 63) == 0) red[t >> 6] = q;
    __syncthreads();
    float stdv = sqrtf((red[0] + red[1] + red[2] + red[3]) * (1.0f / 767.0f));
    float inv = 1.0f / (stdv + EPS);
#pragma unroll
    for (int j = 0; j < 3; ++j) {
        float cj = (j == 0) ? c0 : (j == 1) ? c1 : c2;
        float y = g[t + j * 256] * cj * inv + bb[t + j * 256];
        split_store(y, YH, YL, base + j * 256);
    }
}

// ---------------------------------------------------------------------------
extern "C" void kernel_launch(void* const* d_in, const int* in_sizes, int n_in,
                              void* d_out, int out_size, void* d_ws, size_t ws_size,
                              hipStream_t stream) {
    const float* e    = (const float*)d_in[0];
    const float* f    = (const float*)d_in[1];
    const float* wq   = (const float*)d_in[2];
    const float* wk   = (const float*)d_in[3];
    const float* wv   = (const float*)d_in[4];
    const float* wo   = (const float*)d_in[5];
    const float* bq   = (const float*)d_in[6];
    const float* bk   = (const float*)d_in[7];
    const float* bv   = (const float*)d_in[8];
    const float* bo   = (const float*)d_in[9];
    const float* alg  = (const float*)d_in[10];
    const float* alb  = (const float*)d_in[11];
    const float* fw1  = (const float*)d_in[12];
    const float* fb1  = (const float*)d_in[13];
    const float* fw2  = (const float*)d_in[14];
    const float* fb2  = (const float*)d_in[15];
    const float* flg  = (const float*)d_in[16];
    const float* flb  = (const float*)d_in[17];
    const float* pw   = (const float*)d_in[18];
    const float* pb   = (const float*)d_in[19];
    const float* finw = (const float*)d_in[20];
    const float* finb = (const float*)d_in[21];

    // ---- workspace: 6 hi/lo pairs + split weights + attn partials (~125 MB)
    char* w = (char*)d_ws;
    ushort_t *PH[6], *PL[6];
    for (int i = 0; i < 6; ++i) {
        PH[i] = (ushort_t*)(w + (size_t)(2 * i)     * BSD * 2);
        PL[i] = (ushort_t*)(w + (size_t)(2 * i + 1) * BSD * 2);
    }
    ushort_t* WH = (ushort_t*)(w + (size_t)12 * BSD * 2);
    ushort_t* WL = WH + TOTW;
    float* PO  = (float*)(WL + TOTW);                    // NSPLIT*BHS*DH fp32
    float* PML = PO + (size_t)NSPLIT * BHS * DH;         // NSPLIT*BHS*2 fp32

    k_split_weights<<<(int)(TOTW / 4 / 256), 256, 0, stream>>>(
        wq, wk, wv, wo, fw1, fw2, pw, finw, WH, WL);

    auto gemm = [&](const ushort_t* A1h, const ushort_t* A1l,
                    const ushort_t* A2h, const ushort_t* A2l, int K1,
                    size_t wElemOff, const float* bias,
                    const ushort_t* RresH, const ushort_t* RresL,
                    float* Cf, int trans, ushort_t* Ch, ushort_t* Cl,
                    int M, int N, int K, int act) {
        dim3 g(N / 64, M / 64), blk(256);
        if (act) k_gemm<1><<<g, blk, 0, stream>>>(A1h, A1l, A2h, A2l, K1,
                     WH + wElemOff, WL + wElemOff, bias, RresH, RresL,
                     Cf, trans, Ch, Cl, M, N, K);
        else     k_gemm<0><<<g, blk, 0, stream>>>(A1h, A1l, A2h, A2l, K1,
                     WH + wElemOff, WL + wElemOff, bias, RresH, RresL,
                     Cf, trans, Ch, Cl, M, N, K);
    };

    // One transformer block; all activations as hi/lo pairs.
    auto blk_fn = [&](int qi, int kvi, int ti, int li, int outi) {
        const size_t wOff = (size_t)(ti * 2 + li) * D * D;
        const size_t bOff = (size_t)(ti * 2 + li) * D;
        k_gemm_qkv<<<dim3(D / 64, M2 / 64, 3), 256, 0, stream>>>(
            PH[qi], PL[qi], PH[kvi], PL[kvi], WH, WL, wOff, bq, bk, bv, bOff,
            PH[1], PL[1], PH[2], PL[2], PH[3], PL[3]);
        k_attn_part<<<dim3(S / 64, B * H, NSPLIT), 256, 0, stream>>>(
            PH[1], PL[1], PH[2], PL[2], PH[3], PL[3], PO, PML);
        k_attn_combine<<<(BHS * DH) / 256, 256, 0, stream>>>(PO, PML, PH[4], PL[4]);
        // O-projection + residual(q_in) -> pair 1
        gemm(PH[4], PL[4], nullptr, nullptr, D, OFF_WO + wOff, bo + bOff,
             PH[qi], PL[qi], nullptr, 0, PH[1], PL[1], M2, D, D, 0);
        k_ln<<<M2, 256, 0, stream>>>(PH[1], PL[1], alg + bOff, alb + bOff, PH[2], PL[2]);
        // FFN
        gemm(PH[2], PL[2], nullptr, nullptr, D, OFF_F1 + wOff, fb1 + bOff,
             nullptr, nullptr, nullptr, 0, PH[3], PL[3], M2, D, D, 1);
        gemm(PH[3], PL[3], nullptr, nullptr, D, OFF_F2 + wOff, fb2 + bOff,
             PH[2], PL[2], nullptr, 0, PH[4], PL[4], M2, D, D, 0);
        k_ln<<<M2, 256, 0, stream>>>(PH[4], PL[4], flg + bOff, flb + bOff, PH[outi], PL[outi]);
    };

    auto pass = [&](const float* src, const float* src1, int ti, float* out_sbd) {
        const int TGRID = BSD / 256;
        k_sb2bs<<<TGRID, 256, 0, stream>>>(src, PH[0], PL[0]);
        blk_fn(0, 0, ti, 0, 5);                                  // feats -> pair 5
        k_sb2bs<<<TGRID, 256, 0, stream>>>(src1, PH[0], PL[0]);
        blk_fn(0, 5, ti, 1, 0);                                  // cross -> pair 0
        // pool: flat [1536,1024] @ pw[ti]^T + pb -> pair 1 (APP)
        gemm(PH[0], PL[0], nullptr, nullptr, S, OFF_PW + (size_t)ti * S * S,
             pb + (size_t)ti * S, nullptr, nullptr, nullptr, 0, PH[1], PL[1],
             BSD / S, S, S, 0);
        // final: concat([feats, app]) @ finw^T + finb -> d_out ([S,B,D] direct)
        gemm(PH[5], PL[5], PH[1], PL[1], D, OFF_FIN + (size_t)ti * D * 2 * D,
             finb + (size_t)ti * D, nullptr, nullptr, out_sbd, 1, nullptr, nullptr,
             M2, D, 2 * D, 0);
    };

    float* out = (float*)d_out;
    pass(e, f, 0, out);
    pass(f, e, 1, out + (size_t)BSD);
}